// Round 11
// baseline (1623.078 us; speedup 1.0000x reference)
//
#include <hip/hip_runtime.h>

#define HID  100
#define TT   1024
#define BPW  16    // batches per WG (= MFMA N)
#define WPL  16    // WGs per LSTM -> grid 48
#define NTHR 512   // 8 waves
#define NKK  4     // K = 128: 4 chunks of 32

typedef _Float16 f16x8 __attribute__((ext_vector_type(8)));
typedef float    f32x4 __attribute__((ext_vector_type(4)));

__device__ __forceinline__ float sigf(float x) { return 1.f / (1.f + __expf(-x)); }
__device__ __forceinline__ float tanhf_fast(float x) { return 2.f / (1.f + __expf(-2.f * x)) - 1.f; }

#define MFMA32(A, B, C) __builtin_amdgcn_mfma_f32_16x16x32_f16((A), (B), (C), 0, 0, 0)

// v10: R9's verified math; 8 waves (h-read redundancy 13->8); W held resident
// via IN-LOOP pins (value flows through opaque asm each iteration -> reload
// from memory is no longer provably equivalent -> no remat, unlike R2-R9's
// outside-loop pins). __launch_bounds__(512,2): 256-VGPR budget, ~160 live.
// Wave w owns tiles {w, w+8, w+16}; wave 0 also tile 24; wave 7 x-insert;
// wave 6 x-chunk prefetch. One barrier/step.
__global__ __launch_bounds__(NTHR, 2) void lstm3_kernel(
    const float* __restrict__ x1, const float* __restrict__ x2, const float* __restrict__ x3,
    const float* __restrict__ Wih1, const float* __restrict__ Whh1, const float* __restrict__ bi1, const float* __restrict__ bh1,
    const float* __restrict__ Wih2, const float* __restrict__ Whh2, const float* __restrict__ bi2, const float* __restrict__ bh2,
    const float* __restrict__ Wih3, const float* __restrict__ Whh3, const float* __restrict__ bi3, const float* __restrict__ bh3,
    float* __restrict__ hws)
{
    const int wg    = blockIdx.x;
    const int L     = wg / WPL;
    const int bbase = (wg % WPL) * BPW;
    const int tid   = threadIdx.x;

    const float* x   = (L == 0) ? x1   : (L == 1) ? x2   : x3;
    const float* Wih = (L == 0) ? Wih1 : (L == 1) ? Wih2 : Wih3;
    const float* Whh = (L == 0) ? Whh1 : (L == 1) ? Whh2 : Whh3;
    const float* bi  = (L == 0) ? bi1  : (L == 1) ? bi2  : bi3;
    const float* bh  = (L == 0) ? bh1  : (L == 1) ? bh2  : bh3;

    __shared__ f16x8 Wfq[25 * NKK * 64];      // 102,400 B (fragment order)
    __shared__ f16x8 hfq[2][2][NKK][64];      //  16,384 B (buf, hi/lo, kk, lane)
    __shared__ f32x4 xch[2][64][BPW];         //  32,768 B -> total 151,552 B

    // ---- one-time W staging in fragment order (slot->k: ke = kk*32+g*8+j) ----
    for (int idx = tid; idx < 25 * NKK * 64; idx += NTHR) {
        const int l   = idx & 63;
        const int kkt = idx >> 6;
        const int kk  = kkt & 3, t = kkt >> 2;
        const int m   = l & 15, g = l >> 4;
        const int srow = (m & 3) * 100 + 4 * t + (m >> 2);
        f16x8 q;
#pragma unroll
        for (int j = 0; j < 8; ++j) {
            const int ke = kk * 32 + g * 8 + j;
            float v = 0.f;
            if (ke < 100)       v = Whh[(size_t)srow * HID + ke];
            else if (ke < 104)  v = Wih[(size_t)srow * 4 + (ke - 100)];
            else if (ke == 104) v = bi[srow] + bh[srow];
            else if (ke == 105) { const float bv = bi[srow] + bh[srow];
                                  v = bv - (float)(_Float16)bv; }
            q[j] = (_Float16)v;
        }
        Wfq[idx] = q;
    }
    // ---- h buffers zero ----
    for (int i = tid; i < 2 * 2 * NKK * 64; i += NTHR) {
        f16x8 z;
#pragma unroll
        for (int j = 0; j < 8; ++j) z[j] = (_Float16)0.f;
        ((f16x8*)hfq)[i] = z;
    }
    // ---- x chunk 0 (step-major) ----
    for (int q = tid; q < 64 * BPW; q += NTHR) {
        const int s = q >> 4, b = q & 15;
        xch[0][s][b] = *(const f32x4*)(x + ((size_t)(bbase + b) * TT + s) * 4);
    }
    __syncthreads();
    if (tid < 32) {  // bias ke=104,105 -> kk=3, g=1, j=0,1 (hi, both bufs)
        const int buf = tid >> 4, b = tid & 15;
        _Float16* p = (_Float16*)&hfq[buf][0][3][16 + b];
        p[0] = (_Float16)1.f; p[1] = (_Float16)1.f;
    }
    if (tid < 16) {  // x_0: ke=100..103 -> kk=3, g=0, j=4..7 (buf 0)
        const int b = tid;
        const f32x4 xv = xch[0][0][b];
        _Float16* pH = (_Float16*)&hfq[0][0][3][b];
        _Float16* pL = (_Float16*)&hfq[0][1][3][b];
#pragma unroll
        for (int j = 0; j < 4; ++j) {
            const _Float16 hi = (_Float16)xv[j];
            pH[4 + j] = hi;
            pL[4 + j] = (_Float16)(xv[j] - (float)hi);
        }
    }
    __syncthreads();

    const int wave = tid >> 6, lane = tid & 63;
    const int bat  = lane & 15, g16 = lane >> 4;

    const int  t0 = wave, t1 = wave + 8, t2 = wave + 16;
    const bool v3 = (wave == 0);
    const int  t3 = 24;                      // only wave 0 computes slot 3

    // ---- W fragments -> registers (16 f16x8 = 64 regs) ----
    const f16x8* wp0 = &Wfq[t0 * NKK * 64 + lane];
    const f16x8* wp1 = &Wfq[t1 * NKK * 64 + lane];
    const f16x8* wp2 = &Wfq[t2 * NKK * 64 + lane];
    const f16x8* wp3 = &Wfq[t3 * NKK * 64 + lane];
    f16x8 W00 = wp0[0], W01 = wp0[64], W02 = wp0[128], W03 = wp0[192];
    f16x8 W10 = wp1[0], W11 = wp1[64], W12 = wp1[128], W13 = wp1[192];
    f16x8 W20 = wp2[0], W21 = wp2[64], W22 = wp2[128], W23 = wp2[192];
    f16x8 W30 = wp3[0], W31 = wp3[64], W32 = wp3[128], W33 = wp3[192];

    float cc0 = 0.f, cc1 = 0.f, cc2 = 0.f, cc3 = 0.f;
    float hh0 = 0.f, hh1 = 0.f, hh2 = 0.f, hh3 = 0.f;

    const int c0 = 4 * t0 + g16, c1 = 4 * t1 + g16, c2 = 4 * t2 + g16, c3 = 4 * t3 + g16;

#define UPDATE(AV, CC, HH, C) do {                                             \
        CC = sigf(AV[1]) * CC + sigf(AV[0]) * tanhf_fast(AV[2]);               \
        HH = sigf(AV[3]) * tanhf_fast(CC);                                     \
        const _Float16 hi_ = (_Float16)HH;                                     \
        const _Float16 lo_ = (_Float16)(HH - (float)hi_);                      \
        _Float16* pH_ = (_Float16*)&hfq[nxt][0][(C) >> 5][((((C) & 31) >> 3) << 4) + bat]; \
        _Float16* pL_ = (_Float16*)&hfq[nxt][1][(C) >> 5][((((C) & 31) >> 3) << 4) + bat]; \
        pH_[(C) & 7] = hi_; pL_[(C) & 7] = lo_;                                \
    } while (0)

#pragma unroll 1
    for (int st = 0; st < TT; ++st) {
        const int cur = st & 1, nxt = cur ^ 1;

        // In-loop pins: W becomes loop-carried THROUGH the asm -> no remat.
        asm volatile("" : "+v"(W00), "+v"(W01), "+v"(W02), "+v"(W03));
        asm volatile("" : "+v"(W10), "+v"(W11), "+v"(W12), "+v"(W13));
        asm volatile("" : "+v"(W20), "+v"(W21), "+v"(W22), "+v"(W23));
        asm volatile("" : "+v"(W30), "+v"(W31), "+v"(W32), "+v"(W33));

        // h fragments (shared across this wave's 3-4 tiles): 8 x ds_read_b128
        const f16x8* hb = &hfq[cur][0][0][lane];
        const f16x8 bh0 = hb[0],   bh1 = hb[64],  bh2 = hb[128], bh3 = hb[192];
        const f16x8 bl0 = hb[256], bl1 = hb[320], bl2 = hb[384], bl3 = hb[448];

        f32x4 A0h = {0.f,0.f,0.f,0.f}, A0l = A0h;
        f32x4 A1h = A0h, A1l = A0h, A2h = A0h, A2l = A0h;

        A0h = MFMA32(W00, bh0, A0h);  A0l = MFMA32(W00, bl0, A0l);
        A0h = MFMA32(W01, bh1, A0h);  A0l = MFMA32(W01, bl1, A0l);
        A0h = MFMA32(W02, bh2, A0h);  A0l = MFMA32(W02, bl2, A0l);
        A0h = MFMA32(W03, bh3, A0h);  A0l = MFMA32(W03, bl3, A0l);

        A1h = MFMA32(W10, bh0, A1h);  A1l = MFMA32(W10, bl0, A1l);
        A1h = MFMA32(W11, bh1, A1h);  A1l = MFMA32(W11, bl1, A1l);
        A1h = MFMA32(W12, bh2, A1h);  A1l = MFMA32(W12, bl2, A1l);
        A1h = MFMA32(W13, bh3, A1h);  A1l = MFMA32(W13, bl3, A1l);

        A2h = MFMA32(W20, bh0, A2h);  A2l = MFMA32(W20, bl0, A2l);
        A2h = MFMA32(W21, bh1, A2h);  A2l = MFMA32(W21, bl1, A2l);
        A2h = MFMA32(W22, bh2, A2h);  A2l = MFMA32(W22, bl2, A2l);
        A2h = MFMA32(W23, bh3, A2h);  A2l = MFMA32(W23, bl3, A2l);

        {
            const f32x4 A0 = A0h + A0l;  UPDATE(A0, cc0, hh0, c0);
            const f32x4 A1 = A1h + A1l;  UPDATE(A1, cc1, hh1, c1);
            const f32x4 A2 = A2h + A2l;  UPDATE(A2, cc2, hh2, c2);
        }
        if (v3) {
            f32x4 A3h = {0.f,0.f,0.f,0.f}, A3l = A3h;
            A3h = MFMA32(W30, bh0, A3h);  A3l = MFMA32(W30, bl0, A3l);
            A3h = MFMA32(W31, bh1, A3h);  A3l = MFMA32(W31, bl1, A3l);
            A3h = MFMA32(W32, bh2, A3h);  A3l = MFMA32(W32, bl2, A3l);
            A3h = MFMA32(W33, bh3, A3h);  A3l = MFMA32(W33, bl3, A3l);
            const f32x4 A3 = A3h + A3l;  UPDATE(A3, cc3, hh3, c3);
        }

        if (wave == 7 && lane < 16) {   // x_{st+1}: ke=100..103 -> kk=3, g=0, j=4..7
            const int sp = st + 1;
            const f32x4 xv = xch[(sp >> 6) & 1][sp & 63][lane];
            _Float16* pH = (_Float16*)&hfq[nxt][0][3][lane];
            _Float16* pL = (_Float16*)&hfq[nxt][1][3][lane];
#pragma unroll
            for (int j = 0; j < 4; ++j) {
                const _Float16 hi = (_Float16)xv[j];
                pH[4 + j] = hi;
                pL[4 + j] = (_Float16)(xv[j] - (float)hi);
            }
        }
        if (wave == 6 && (st & 63) == 0) {   // prefetch next 64-step x chunk
            const int nc = (st >> 6) + 1;
            if (nc < TT / 64) {
#pragma unroll
                for (int it = 0; it < 16; ++it) {
                    const int q = it * 64 + lane;
                    const int s = q >> 4, b = q & 15;
                    xch[nc & 1][s][b] =
                        *(const f32x4*)(x + ((size_t)(bbase + b) * TT + nc * 64 + s) * 4);
                }
            }
        }
        __syncthreads();
    }
#undef UPDATE

    // ---- final h -> workspace [b_global][300], column L*100 + cell ----
    {
        const size_t ob = (size_t)(bbase + bat) * 300 + L * HID;
        hws[ob + c0] = hh0;
        hws[ob + c1] = hh1;
        hws[ob + c2] = hh2;
        if (v3) hws[ob + c3] = hh3;
    }
}

// out[b][o] = relu(fc_b[o] + sum_j h[b][j] * fc_W[o][j]),  j < 300, o < 12
__global__ __launch_bounds__(64, 1) void fc_kernel(
    const float* __restrict__ hws, const float* __restrict__ fcW,
    const float* __restrict__ fcb, float* __restrict__ out)
{
    const int b = blockIdx.x, lane = threadIdx.x;
    float hv[5];
#pragma unroll
    for (int c = 0; c < 5; c++) {
        const int j = lane + 64 * c;
        hv[c] = (j < 300) ? hws[b * 300 + j] : 0.f;
    }
#pragma unroll
    for (int o = 0; o < 12; o++) {
        float a = 0.f;
#pragma unroll
        for (int c = 0; c < 5; c++) {
            const int j = lane + 64 * c;
            const float wv = (j < 300) ? fcW[o * 300 + j] : 0.f;
            a += hv[c] * wv;
        }
#pragma unroll
        for (int off = 32; off > 0; off >>= 1) a += __shfl_xor(a, off, 64);
        if (lane == 0) out[b * 12 + o] = fmaxf(a + fcb[o], 0.f);
    }
}

extern "C" void kernel_launch(void* const* d_in, const int* in_sizes, int n_in,
                              void* d_out, int out_size, void* d_ws, size_t ws_size,
                              hipStream_t stream)
{
    const float* x1   = (const float*)d_in[0];
    const float* x2   = (const float*)d_in[1];
    const float* x3   = (const float*)d_in[2];
    const float* Wih1 = (const float*)d_in[3];
    const float* Whh1 = (const float*)d_in[4];
    const float* bi1  = (const float*)d_in[5];
    const float* bh1  = (const float*)d_in[6];
    const float* Wih2 = (const float*)d_in[7];
    const float* Whh2 = (const float*)d_in[8];
    const float* bi2  = (const float*)d_in[9];
    const float* bh2  = (const float*)d_in[10];
    const float* Wih3 = (const float*)d_in[11];
    const float* Whh3 = (const float*)d_in[12];
    const float* bi3  = (const float*)d_in[13];
    const float* bh3  = (const float*)d_in[14];
    const float* fcW  = (const float*)d_in[15];
    const float* fcb  = (const float*)d_in[16];

    float* hws = (float*)d_ws;  // 256*300 floats = 300 KiB

    lstm3_kernel<<<3 * WPL, NTHR, 0, stream>>>(x1, x2, x3,
                                               Wih1, Whh1, bi1, bh1,
                                               Wih2, Whh2, bi2, bh2,
                                               Wih3, Whh3, bi3, bh3, hws);
    fc_kernel<<<256, 64, 0, stream>>>(hws, fcW, fcb, (float*)d_out);
}